// Round 1
// 565.095 us; speedup vs baseline: 1.0637x; 1.0637x over previous
//
#include <hip/hip_runtime.h>

// EdgeNorm, round 5: same counting-sort pipeline, occupancy-fixed stats.
//
// Round-4 lesson (rocprof): stats_kernel was 359us with VALUBusy 0.43%,
// HBM 6.5%, LDS conflicts 0, OccupancyPercent 20% (= 1.6 waves/SIMD).
// Pure latency serialization on the random scores[e] gather: grid was only
// 784 blocks (3/CU) each holding 34KB LDS. Fix: bucket 512 -> 128 nodes
// (KSHIFT 9 -> 7). LDS/block 34816 -> 8704B, grid 784 -> 3128 blocks, so
// residency is wave-limited at 8 blocks/CU = 32 waves/CU (100%) instead of
// block-limited at ~20%. Total ws footprint unchanged (~53MB): records 16MB,
// partials 27MB. VGPR 52 <= 64 keeps the 8-waves/SIMD ceiling reachable.
//
// Pipeline:
//   1. count   : LDS histogram of dst>>7 per 3128-edge chunk -> counts[b][blk]
//   2. scan    : per-bucket exclusive prefix over blocks (+ totals[b])
//   3. scatter : records[b*CAPB + off] = (dst&127)<<23 | e   (u32, e<2^23)
//   4. stats   : block (part,bucket) walks dense records, gathers scores[e],
//                LDS-accumulates 128x17 tile, plain stores to partials
//   5. coeff   : reduce partials; AB[node] = [A(8)|B(8)] one 64B line
//   6. edge_out: out = A[dst]*x + B[dst]

#define NHEADS  8
#define KSHIFT  7
#define KNODES  128
#define SLOTS   17            // 8 sum + 8 sumsq + 1 count
#define NNODES  100000
#define NB      782           // ceil(100000/128)
#define CBLK    1024          // count/scatter blocks
#define CAPB    5120          // per-bucket capacity (mean 4092, sigma ~64)
#define PARTS_B 4

__global__ __launch_bounds__(256)
void count_kernel(const int* __restrict__ dst, unsigned* __restrict__ counts,
                  int E, int chunk) {
    __shared__ unsigned hist[NB];
    for (int i = threadIdx.x; i < NB; i += 256) hist[i] = 0u;
    __syncthreads();
    const int blk = blockIdx.x;
    const int s0 = blk * chunk;
    const int s1 = min(s0 + chunk, E);
    for (int i = s0 + (int)threadIdx.x * 4; i < s1; i += 256 * 4) {
        if (i + 4 <= s1) {
            int4 d = *reinterpret_cast<const int4*>(dst + i);
            atomicAdd(&hist[(unsigned)d.x >> KSHIFT], 1u);
            atomicAdd(&hist[(unsigned)d.y >> KSHIFT], 1u);
            atomicAdd(&hist[(unsigned)d.z >> KSHIFT], 1u);
            atomicAdd(&hist[(unsigned)d.w >> KSHIFT], 1u);
        } else {
            for (int j = i; j < s1; ++j)
                atomicAdd(&hist[(unsigned)dst[j] >> KSHIFT], 1u);
        }
    }
    __syncthreads();
    for (int b = threadIdx.x; b < NB; b += 256)
        counts[(size_t)b * CBLK + blk] = hist[b];
}

// One block per bucket: exclusive scan of counts[b][0..CBLK) in place.
__global__ __launch_bounds__(256)
void scan_kernel(unsigned* __restrict__ counts, unsigned* __restrict__ totals) {
    __shared__ unsigned sc[256];
    const int b = blockIdx.x;
    const size_t base = (size_t)b * CBLK + (size_t)threadIdx.x * 4;
    uint4 v = *reinterpret_cast<uint4*>(counts + base);
    unsigned s = v.x + v.y + v.z + v.w;
    sc[threadIdx.x] = s;
    __syncthreads();
    for (int off = 1; off < 256; off <<= 1) {
        unsigned t = (threadIdx.x >= (unsigned)off) ? sc[threadIdx.x - off] : 0u;
        __syncthreads();
        sc[threadIdx.x] += t;
        __syncthreads();
    }
    unsigned excl = sc[threadIdx.x] - s;
    uint4 o;
    o.x = excl;
    o.y = excl + v.x;
    o.z = o.y + v.y;
    o.w = o.z + v.z;
    *reinterpret_cast<uint4*>(counts + base) = o;
    if (threadIdx.x == 255) totals[b] = sc[255];
}

__global__ __launch_bounds__(256)
void scatter_kernel(const int* __restrict__ dst, const unsigned* __restrict__ counts,
                    unsigned* __restrict__ records, int E, int chunk) {
    __shared__ unsigned cur[NB];
    const int blk = blockIdx.x;
    for (int b = threadIdx.x; b < NB; b += 256)
        cur[b] = counts[(size_t)b * CBLK + blk];
    __syncthreads();
    const int s0 = blk * chunk;
    const int s1 = min(s0 + chunk, E);
    for (int i = s0 + (int)threadIdx.x; i < s1; i += 256) {
        int d = dst[i];
        unsigned b = (unsigned)d >> KSHIFT;
        unsigned off = atomicAdd(&cur[b], 1u);
        if (off < CAPB)   // statically impossible for uniform dst; guards corruption
            records[(size_t)b * CAPB + off] =
                ((unsigned)(d & (KNODES - 1)) << 23) | (unsigned)i;
    }
}

__global__ __launch_bounds__(256)
void stats_kernel(const unsigned* __restrict__ records,
                  const unsigned* __restrict__ totals,
                  const float* __restrict__ scores,
                  float* __restrict__ partials) {
    __shared__ float st[KNODES * SLOTS];     // 8704 B -> wave-limited occupancy
    const int part = blockIdx.x;
    const int b    = blockIdx.y;
    float4* stv = reinterpret_cast<float4*>(st);
    for (int i = threadIdx.x; i < (KNODES * SLOTS) / 4; i += 256)
        stv[i] = float4{0.f, 0.f, 0.f, 0.f};
    __syncthreads();

    const int cnt = (int)totals[b];
    const int seg = (cnt + PARTS_B - 1) / PARTS_B;
    const int i0 = part * seg;
    const int i1 = min(cnt, i0 + seg);
    const unsigned* rec = records + (size_t)b * CAPB;

    // Dense walk; two edges per iteration for load-level parallelism.
    for (int i = i0 + (int)threadIdx.x; i < i1; i += 512) {
        int j = i + 256;
        unsigned r0 = rec[i];
        unsigned r1 = (j < i1) ? rec[j] : 0u;
        const float4* p0 = reinterpret_cast<const float4*>(
            scores + (size_t)(r0 & 0x7FFFFFu) * NHEADS);
        float4 a0 = p0[0], c0 = p0[1];
        float4 a1, c1;
        if (j < i1) {
            const float4* p1 = reinterpret_cast<const float4*>(
                scores + (size_t)(r1 & 0x7FFFFFu) * NHEADS);
            a1 = p1[0]; c1 = p1[1];
        }
        {
            float* s = st + (int)(r0 >> 23) * SLOTS;   // stride 17: odd
            atomicAdd(s + 0,  a0.x);       atomicAdd(s + 1,  a0.y);
            atomicAdd(s + 2,  a0.z);       atomicAdd(s + 3,  a0.w);
            atomicAdd(s + 4,  c0.x);       atomicAdd(s + 5,  c0.y);
            atomicAdd(s + 6,  c0.z);       atomicAdd(s + 7,  c0.w);
            atomicAdd(s + 8,  a0.x * a0.x); atomicAdd(s + 9,  a0.y * a0.y);
            atomicAdd(s + 10, a0.z * a0.z); atomicAdd(s + 11, a0.w * a0.w);
            atomicAdd(s + 12, c0.x * c0.x); atomicAdd(s + 13, c0.y * c0.y);
            atomicAdd(s + 14, c0.z * c0.z); atomicAdd(s + 15, c0.w * c0.w);
            atomicAdd(s + 16, 1.0f);
        }
        if (j < i1) {
            float* s = st + (int)(r1 >> 23) * SLOTS;
            atomicAdd(s + 0,  a1.x);       atomicAdd(s + 1,  a1.y);
            atomicAdd(s + 2,  a1.z);       atomicAdd(s + 3,  a1.w);
            atomicAdd(s + 4,  c1.x);       atomicAdd(s + 5,  c1.y);
            atomicAdd(s + 6,  c1.z);       atomicAdd(s + 7,  c1.w);
            atomicAdd(s + 8,  a1.x * a1.x); atomicAdd(s + 9,  a1.y * a1.y);
            atomicAdd(s + 10, a1.z * a1.z); atomicAdd(s + 11, a1.w * a1.w);
            atomicAdd(s + 12, c1.x * c1.x); atomicAdd(s + 13, c1.y * c1.y);
            atomicAdd(s + 14, c1.z * c1.z); atomicAdd(s + 15, c1.w * c1.w);
            atomicAdd(s + 16, 1.0f);
        }
    }
    __syncthreads();

    float* out = partials + ((size_t)b * PARTS_B + part) * (KNODES * SLOTS);
    float4* outv = reinterpret_cast<float4*>(out);
    for (int i = threadIdx.x; i < (KNODES * SLOTS) / 4; i += 256)
        outv[i] = stv[i];
}

// AB layout: per node 16 floats = one 64B line: [A(8) | B(8)].
__global__ __launch_bounds__(256)
void coeff_kernel(const float* __restrict__ partials,
                  const float* __restrict__ gain,
                  const float* __restrict__ bias,
                  float* __restrict__ AB, int total) {
    int i = blockIdx.x * 256 + threadIdx.x;
    if (i >= total) return;
    int node = i >> 3, h = i & 7;
    int b = node >> KSHIFT;
    int k = node & (KNODES - 1);
    const float* base =
        partials + (size_t)b * PARTS_B * (KNODES * SLOTS) + (size_t)k * SLOTS;
    float s = 0.f, q = 0.f, c = 0.f;
    #pragma unroll
    for (int p = 0; p < PARTS_B; p++) {
        const float* pp = base + (size_t)p * (KNODES * SLOTS);
        s += pp[h];
        q += pp[8 + h];
        c += pp[16];
    }
    float cm   = fmaxf(c, 1.0f);                 // ref: sums / max(counts,1)
    float mean = s / cm;
    float var  = fmaxf(q - s * mean, 0.0f);      // one-pass variance, clamped
    float inv  = 1.0f / fmaxf(sqrtf(var / cm), 1e-5f);
    float a = gain[h] * inv;
    AB[(size_t)node * 16 + h]     = a;
    AB[(size_t)node * 16 + 8 + h] = fmaf(-a, mean, bias[h]);
}

__global__ __launch_bounds__(256)
void edge_out_kernel(const float* __restrict__ scores,
                     const int* __restrict__ dst,
                     const float* __restrict__ AB,
                     float* __restrict__ out,
                     int num_edges) {
    int e = blockIdx.x * 256 + threadIdx.x;
    if (e >= num_edges) return;
    int d = dst[e];
    const float4* px  = reinterpret_cast<const float4*>(scores + (size_t)e * NHEADS);
    const float4* pab = reinterpret_cast<const float4*>(AB + (size_t)d * 16);
    float4 x0 = px[0], x1 = px[1];
    float4 a0 = pab[0], a1 = pab[1];
    float4 b0 = pab[2], b1 = pab[3];
    float4 o0, o1;
    o0.x = fmaf(a0.x, x0.x, b0.x);
    o0.y = fmaf(a0.y, x0.y, b0.y);
    o0.z = fmaf(a0.z, x0.z, b0.z);
    o0.w = fmaf(a0.w, x0.w, b0.w);
    o1.x = fmaf(a1.x, x1.x, b1.x);
    o1.y = fmaf(a1.y, x1.y, b1.y);
    o1.z = fmaf(a1.z, x1.z, b1.z);
    o1.w = fmaf(a1.w, x1.w, b1.w);
    float4* po = reinterpret_cast<float4*>(out + (size_t)e * NHEADS);
    po[0] = o0;
    po[1] = o1;
}

// ---- global-atomic fallback (only if ws too small / E too large) ----------
__global__ void edge_stats_fallback(const float* __restrict__ scores,
                                    const int* __restrict__ dst,
                                    float* __restrict__ sums,
                                    float* __restrict__ sumsq,
                                    int* __restrict__ counts,
                                    int num_edges) {
    int e = blockIdx.x * blockDim.x + threadIdx.x;
    if (e >= num_edges) return;
    int d = dst[e];
    const float4* p = reinterpret_cast<const float4*>(scores + (size_t)e * NHEADS);
    float4 x0 = p[0], x1 = p[1];
    float* s = sums  + (size_t)d * NHEADS;
    float* q = sumsq + (size_t)d * NHEADS;
    atomicAdd(s + 0, x0.x); atomicAdd(s + 1, x0.y);
    atomicAdd(s + 2, x0.z); atomicAdd(s + 3, x0.w);
    atomicAdd(s + 4, x1.x); atomicAdd(s + 5, x1.y);
    atomicAdd(s + 6, x1.z); atomicAdd(s + 7, x1.w);
    atomicAdd(q + 0, x0.x * x0.x); atomicAdd(q + 1, x0.y * x0.y);
    atomicAdd(q + 2, x0.z * x0.z); atomicAdd(q + 3, x0.w * x0.w);
    atomicAdd(q + 4, x1.x * x1.x); atomicAdd(q + 5, x1.y * x1.y);
    atomicAdd(q + 6, x1.z * x1.z); atomicAdd(q + 7, x1.w * x1.w);
    atomicAdd(counts + d, 1);
}

__global__ void coeff_fallback(const float* __restrict__ sums,
                               const float* __restrict__ sumsq,
                               const int* __restrict__ counts,
                               const float* __restrict__ gain,
                               const float* __restrict__ bias,
                               float* __restrict__ AB, int total) {
    int i = blockIdx.x * blockDim.x + threadIdx.x;
    if (i >= total) return;
    int h = i & (NHEADS - 1);
    int node = i >> 3;
    float cm = fmaxf((float)counts[node], 1.0f);
    float s = sums[i];
    float mean = s / cm;
    float var_sum = fmaxf(sumsq[i] - s * mean, 0.0f);
    float inv = 1.0f / fmaxf(sqrtf(var_sum / cm), 1e-5f);
    float a = gain[h] * inv;
    AB[(size_t)node * 16 + h]     = a;
    AB[(size_t)node * 16 + 8 + h] = fmaf(-a, mean, bias[h]);
}
// ---------------------------------------------------------------------------

extern "C" void kernel_launch(void* const* d_in, const int* in_sizes, int n_in,
                              void* d_out, int out_size, void* d_ws, size_t ws_size,
                              hipStream_t stream) {
    const float* scores = (const float*)d_in[0];
    const float* gain   = (const float*)d_in[1];
    const float* bias   = (const float*)d_in[2];
    const int*   dst    = (const int*)d_in[3];

    const int E  = in_sizes[3];
    const int N  = NNODES;
    const int NH = N * NHEADS;

    // ws layout (256B-aligned sections):
    //   AB       : N*16 f32                     6.40 MB
    //   counts   : NB*CBLK u32                  3.20 MB
    //   totals   : NB u32
    //   records  : NB*CAPB u32                 16.02 MB
    //   partials : NB*PARTS_B*KNODES*SLOTS f32 27.23 MB
    size_t off = 0;
    float* AB = (float*)d_ws;                     off += (size_t)N * 16 * 4;
    off = (off + 255) & ~(size_t)255;
    unsigned* counts = (unsigned*)((char*)d_ws + off); off += (size_t)NB * CBLK * 4;
    off = (off + 255) & ~(size_t)255;
    unsigned* totals = (unsigned*)((char*)d_ws + off); off += (size_t)NB * 4;
    off = (off + 255) & ~(size_t)255;
    unsigned* records = (unsigned*)((char*)d_ws + off); off += (size_t)NB * CAPB * 4;
    off = (off + 255) & ~(size_t)255;
    float* partials = (float*)((char*)d_ws + off);
    off += (size_t)NB * PARTS_B * KNODES * SLOTS * 4;

    const int B = 256;
    const bool fits = (off <= ws_size) && (E < (1 << 23)) &&
                      ((size_t)E <= (size_t)NB * CAPB);

    if (fits) {
        int chunk = (((E + CBLK - 1) / CBLK) + 3) & ~3;
        count_kernel<<<CBLK, B, 0, stream>>>(dst, counts, E, chunk);
        scan_kernel<<<NB, B, 0, stream>>>(counts, totals);
        scatter_kernel<<<CBLK, B, 0, stream>>>(dst, counts, records, E, chunk);
        dim3 gs(PARTS_B, NB);
        stats_kernel<<<gs, B, 0, stream>>>(records, totals, scores, partials);
        coeff_kernel<<<(NH + B - 1) / B, B, 0, stream>>>(partials, gain, bias, AB, NH);
        edge_out_kernel<<<(E + B - 1) / B, B, 0, stream>>>(scores, dst, AB, (float*)d_out, E);
    } else {
        float* sums  = (float*)((char*)d_ws + (size_t)N * 16 * 4);
        float* sumsq = sums + NH;
        int*   cnts  = (int*)(sumsq + NH);
        hipMemsetAsync(sums, 0,
                       (size_t)(2 * NH) * sizeof(float) + (size_t)N * sizeof(int), stream);
        int blocks_e = (E + B - 1) / B;
        edge_stats_fallback<<<blocks_e, B, 0, stream>>>(scores, dst, sums, sumsq, cnts, E);
        coeff_fallback<<<(NH + B - 1) / B, B, 0, stream>>>(sums, sumsq, cnts, gain, bias, AB, NH);
        edge_out_kernel<<<blocks_e, B, 0, stream>>>(scores, dst, AB, (float*)d_out, E);
    }
}